// Round 6
// baseline (214.530 us; speedup 1.0000x reference)
//
#include <hip/hip_runtime.h>
#include <math.h>

// Problem constants
#define BN   4
#define CN   256
#define HN   128
#define WN   128
#define COMP 64
#define KK   25      // K*K taps
#define HO   64
#define WO   64
#define NZC  8       // K-splits for MFMA conv (32 ch each)

// ---------------- fast-path workspace layout (float offsets) ----------------
// wA : 9*16*64*8 bf16 A-fragments = 36864 floats
// tb : 225 floats (+pad to 256)
// pl : NZC * BN*HO*KK*64 partial logits
// sm : BN*HO*KK*64 softmaxed mask
// xT : BN*HN*WN*CN bf16 (NHWC) = 8388608 float-slots
#define TB_OFF    36864
#define PL_OFF    37120
#define PL_SLICE  (BN * HO * KK * 64)              // 409600
#define SM_OFF    (PL_OFF + NZC * PL_SLICE)        // 3313920
#define XT_OFF    (SM_OFF + PL_SLICE)              // 3723520
#define WS_NEED   ((size_t)(XT_OFF + (size_t)BN * HN * WN * CN / 2) * 4)

typedef short v8s  __attribute__((ext_vector_type(8)));
typedef float v16f __attribute__((ext_vector_type(16)));

__device__ inline ushort f2bf(float f) {       // fp32 -> bf16 bits, RNE
  unsigned u = __float_as_uint(f);
  return (ushort)((u + 0x7fffu + ((u >> 16) & 1u)) >> 16);
}

// ---------------------------------------------------------------------------
// Compose: bake w2*w1 into MFMA A-fragment order (bf16) + tb.
// Grid (9 taps, 16 chunks), 64 threads. m=lane&31, half=lane>>5.
// wA[((t*16+chunk)*64+lane)*8 + j] = W_t[c = chunk*16+half*8+j][m]  (m<25)
// ---------------------------------------------------------------------------
__global__ __launch_bounds__(64) void compose_mfma(
    const float* __restrict__ w1, const float* __restrict__ b1,
    const float* __restrict__ w2, float* __restrict__ ws) {
  const int t = blockIdx.x, chunk = blockIdx.y;
  const int lane = threadIdx.x;
  const int m = lane & 31, half = lane >> 5;
  const int c0 = chunk * 16 + half * 8;
  float acc[8] = {0.f, 0.f, 0.f, 0.f, 0.f, 0.f, 0.f, 0.f};
  if (m < KK) {
    for (int k = 0; k < COMP; ++k) {
      float wv = w2[(size_t)(m * COMP + k) * 9 + t];
      const float* w1r = w1 + (size_t)k * CN + c0;
      float4 a = *(const float4*)w1r;
      float4 bq = *(const float4*)(w1r + 4);
      acc[0] += wv * a.x;  acc[1] += wv * a.y;
      acc[2] += wv * a.z;  acc[3] += wv * a.w;
      acc[4] += wv * bq.x; acc[5] += wv * bq.y;
      acc[6] += wv * bq.z; acc[7] += wv * bq.w;
    }
  }
  ushort* wA = (ushort*)ws;
  ushort pk[8];
#pragma unroll
  for (int j = 0; j < 8; ++j) pk[j] = f2bf(acc[j]);
  *(ushort4*)(wA + ((size_t)(t * 16 + chunk) * 64 + lane) * 8) =
      make_ushort4(pk[0], pk[1], pk[2], pk[3]);
  *(ushort4*)(wA + ((size_t)(t * 16 + chunk) * 64 + lane) * 8 + 4) =
      make_ushort4(pk[4], pk[5], pk[6], pk[7]);
  if (chunk == 0 && lane < KK) {
    float tbv = 0.f;
    for (int k = 0; k < COMP; ++k)
      tbv += w2[(size_t)(lane * COMP + k) * 9 + t] * b1[k];
    ws[TB_OFF + lane * 9 + t] = tbv;
  }
}

// ---------------------------------------------------------------------------
// Transpose x NCHW fp32 -> xT NHWC bf16. Grid (8, HN, BN), 256 threads.
// ---------------------------------------------------------------------------
__global__ __launch_bounds__(256) void transpose_x(
    const float* __restrict__ x, float* __restrict__ ws) {
  __shared__ float st[64][65];
  const int wt = blockIdx.x & 1, ct = blockIdx.x >> 1;
  const int h = blockIdx.y, b = blockIdx.z;
  const int tid = threadIdx.x;
  const int w0 = wt * 64, c0 = ct * 64;
  {
    const int wl = tid & 63, cw = tid >> 6;
#pragma unroll
    for (int i = 0; i < 16; ++i) {
      int cl = cw * 16 + i;
      st[cl][wl] = x[((size_t)(b * CN + c0 + cl) * HN + h) * WN + w0 + wl];
    }
  }
  __syncthreads();
  ushort* xT = (ushort*)(ws + XT_OFF);
  const int cg = tid & 15, wl0 = tid >> 4;
#pragma unroll
  for (int wi = 0; wi < 4; ++wi) {
    int wl = wl0 + wi * 16;
    ushort4 o = make_ushort4(f2bf(st[cg * 4 + 0][wl]), f2bf(st[cg * 4 + 1][wl]),
                             f2bf(st[cg * 4 + 2][wl]), f2bf(st[cg * 4 + 3][wl]));
    *(ushort4*)(xT + ((size_t)((b * HN + h) * WN + w0 + wl)) * CN + c0 + cg * 4) = o;
  }
}

// ---------------------------------------------------------------------------
// MFMA conv: 9 tap-GEMMs, 32(m) x 32(px) per wave, K=32 channels (z-slice).
// Grid (16 = wt|z<<1, HO, BN) = 4096 one-wave blocks -> 16 waves/CU.
// C/D layout: col(px)=lane&31, row(m)=(reg&3)+8*(reg>>2)+4*(lane>>5).
// ---------------------------------------------------------------------------
__global__ __launch_bounds__(64) void conv_mfma(
    const float* __restrict__ ws, float* __restrict__ pl) {
  const int wt = blockIdx.x & 1, z = blockIdx.x >> 1;   // z 0..7
  const int ho = blockIdx.y, b = blockIdx.z;
  const int lane = threadIdx.x;
  const int n = lane & 31, half = lane >> 5;
  const int wo = wt * 32 + n;
  const ushort* xT = (const ushort*)(ws + XT_OFF);
  const ushort* wA = (const ushort*)ws;
  const int coff = z * 32 + half * 8;
  const v8s zero8 = {};
  v16f acc = {};

#pragma unroll
  for (int dr = 0; dr < 3; ++dr) {
    const int r = 2 * ho + dr - 1;
    if (r < 0) continue;                       // wave-uniform (ho==0, dr==0)
#pragma unroll
    for (int dc = 0; dc < 3; ++dc) {
      const int t = dr * 3 + dc;
      const int q = 2 * wo + dc - 1;
      const bool bad = q < 0;                  // only lane wo==0, dc==0
      const int qc = bad ? 0 : q;
      const ushort* bp = xT + ((size_t)((b * HN + r) * WN + qc)) * CN + coff;
      const ushort* ap = wA + ((size_t)(t * 16 + z * 2) * 64 + lane) * 8;
      v8s bf0 = *(const v8s*)bp;
      v8s bf1 = *(const v8s*)(bp + 16);
      v8s af0 = *(const v8s*)ap;
      v8s af1 = *(const v8s*)(ap + 512);
      if (dc == 0 && bad) { bf0 = zero8; bf1 = zero8; }
      acc = __builtin_amdgcn_mfma_f32_32x32x16_bf16(af0, bf0, acc, 0, 0, 0);
      acc = __builtin_amdgcn_mfma_f32_32x32x16_bf16(af1, bf1, acc, 0, 0, 0);
    }
  }

  float* dst = pl + (size_t)z * PL_SLICE + ((size_t)(b * HO + ho) * KK) * 64 + wo;
#pragma unroll
  for (int rg = 0; rg < 16; ++rg) {
    int m = (rg & 3) + 8 * (rg >> 2) + 4 * half;
    if (m < KK) dst[(size_t)m * 64] = acc[rg];
  }
}

// ---------------------------------------------------------------------------
// Softmax: sum 8 pl slices + bias/border terms -> softmax(25) -> sm.
// Grid (HO, BN), 64 threads, lane = wo.
// ---------------------------------------------------------------------------
__global__ __launch_bounds__(64) void softmax_kernel(
    const float* __restrict__ b2, const float* __restrict__ tb,
    const float* __restrict__ pl, float* __restrict__ sm) {
  const int ho = blockIdx.x, b = blockIdx.y;
  const int wo = threadIdx.x;
  const float vr0 = (ho > 0) ? 1.f : 0.f;
  const float vq0 = (wo > 0) ? 1.f : 0.f;
  const float* base = pl + ((size_t)(b * HO + ho) * KK) * 64 + wo;
  float logit[KK];
  float mx = -1e30f;
#pragma unroll
  for (int m = 0; m < KK; ++m) {
    const float* t9 = tb + m * 9;
    float l = b2[m]
            + vr0 * (vq0 * t9[0] + t9[1] + t9[2])
            +       (vq0 * t9[3] + t9[4] + t9[5])
            +       (vq0 * t9[6] + t9[7] + t9[8]);
#pragma unroll
    for (int s = 0; s < NZC; ++s)
      l += base[(size_t)s * PL_SLICE + (size_t)m * 64];
    logit[m] = l;
    mx = fmaxf(mx, l);
  }
  float ssum = 0.f;
#pragma unroll
  for (int m = 0; m < KK; ++m) {
    float e = __expf(logit[m] - mx);
    logit[m] = e;
    ssum += e;
  }
  float inv = 1.f / ssum;
  float* dst = sm + ((size_t)(b * HO + ho) * KK) * 64 + wo;
#pragma unroll
  for (int m = 0; m < KK; ++m) dst[(size_t)m * 64] = logit[m] * inv;
}

// ---------------------------------------------------------------------------
// CARAFE gather: barrier-free, LDS-free. Grid (HO, BN, 4), 512 threads.
// Wave wv owns 8 channels (c = z*64 + wv*8 + ci); lane = wo.
// Mask in registers (25 coalesced loads); x via float2 + shuffles.
// ---------------------------------------------------------------------------
__global__ __launch_bounds__(512) void gather_kernel(
    const float* __restrict__ x, const float* __restrict__ sm,
    float* __restrict__ out) {
  const int ho  = blockIdx.x;
  const int b   = blockIdx.y;
  const int z   = blockIdx.z;
  const int tid = threadIdx.x;
  const int wo  = tid & 63;
  const int wv  = tid >> 6;                    // 0..7
  const int c_base = __builtin_amdgcn_readfirstlane(z * 64 + wv * 8);

  float smr[KK];
  {
    const float* smp = sm + ((size_t)(b * HO + ho) * KK) * 64 + wo;
#pragma unroll
    for (int m = 0; m < KK; ++m) smr[m] = smp[(size_t)m * 64];
  }

  const float* __restrict__ xb = x + (size_t)(b * CN) * (HN * WN);
  const int col = 2 * wo;
  const float wok = (wo > 0) ? 1.f : 0.f;
  const float w63 = (wo < 63) ? 1.f : 0.f;

  float2 g[2][5];
  auto load_g = [&](int ci, float2* dst) {
    const float* xc = xb + (size_t)(c_base + ci) * (HN * WN);
#pragma unroll
    for (int i = 0; i < 5; ++i) {
      int r = 2 * ho - 2 + i;
      dst[i] = (r >= 0 && r < HN) ? *(const float2*)(xc + r * WN + col)
                                  : make_float2(0.f, 0.f);
    }
  };
  load_g(0, g[0]);
  load_g(1, g[1]);

  for (int ci = 0; ci < 8; ++ci) {
    float2 v[5];
#pragma unroll
    for (int i = 0; i < 5; ++i) v[i] = g[ci & 1][i];
    if (ci + 2 < 8) load_g(ci + 2, g[ci & 1]);

    float acc2 = 0.f;
#pragma unroll
    for (int i = 0; i < 5; ++i) {
      float lx = wok * __shfl_up(v[i].x, 1, 64);    // col 2wo-2
      float ly = wok * __shfl_up(v[i].y, 1, 64);    // col 2wo-1
      float rx = w63 * __shfl_down(v[i].x, 1, 64);  // col 2wo+2
      acc2 += lx * smr[i * 5 + 0] + ly * smr[i * 5 + 1]
            + v[i].x * smr[i * 5 + 2] + v[i].y * smr[i * 5 + 3]
            + rx * smr[i * 5 + 4];
    }
    out[(((size_t)(b * CN + c_base + ci)) * HO + ho) * WO + wo] = acc2;
  }
}

// ============================ FALLBACK PATH ================================
// Round-2 proven kernels (used only if ws_size < WS_NEED).
#define FB_WSTRIDE 240
#define FB_TB_OFF  (256 * FB_WSTRIDE)

__global__ __launch_bounds__(256) void compose_w_fb(
    const float* __restrict__ w1, const float* __restrict__ b1,
    const float* __restrict__ w2, float* __restrict__ ws) {
  int mt = blockIdx.x, c = threadIdx.x;
  float acc = 0.f;
#pragma unroll 8
  for (int k = 0; k < COMP; ++k)
    acc += w2[(size_t)(mt / 9 * COMP + k) * 9 + (mt % 9)] * w1[k * CN + c];
  ws[c * FB_WSTRIDE + mt] = acc;
  if (mt < FB_WSTRIDE - 225) ws[c * FB_WSTRIDE + 225 + mt] = 0.f;
  if (c == 0) {
    float tbv = 0.f;
    for (int k = 0; k < COMP; ++k)
      tbv += w2[(size_t)(mt / 9 * COMP + k) * 9 + (mt % 9)] * b1[k];
    ws[FB_TB_OFF + mt] = tbv;
  }
}

__global__ __launch_bounds__(1024, 4) void fused_fb(
    const float* __restrict__ x, const float* __restrict__ b2,
    const float* __restrict__ ws, float* __restrict__ out) {
  const int ho = blockIdx.x, b = blockIdx.y, tid = threadIdx.x;
  const int wo = tid & 63, wv = tid >> 6;
  const int c_base = __builtin_amdgcn_readfirstlane(wv * 16);
  const float* __restrict__ w2c = ws;
  const float* __restrict__ tb  = ws + FB_TB_OFF;
  __shared__ float red[8 * KK * 64];
  __shared__ float sm[KK * 64];
  const float* __restrict__ xb = x + (size_t)(b * CN) * (HN * WN);
  const int col = 2 * wo;
  float acc[KK];
#pragma unroll
  for (int m = 0; m < KK; ++m) acc[m] = 0.f;
  float2 xbuf[2][3];
  auto load_ch = [&](int ci, float2* dst) {
    const float* xc = xb + (size_t)(c_base + ci) * (HN * WN);
    dst[0] = (ho > 0) ? *(const float2*)(xc + (2 * ho - 1) * WN + col)
                      : make_float2(0.f, 0.f);
    dst[1] = *(const float2*)(xc + (2 * ho) * WN + col);
    dst[2] = *(const float2*)(xc + (2 * ho + 1) * WN + col);
  };
  load_ch(0, xbuf[0]);
  load_ch(1, xbuf[1]);
  const float wok = (wo > 0) ? 1.f : 0.f;
  for (int ci = 0; ci < 16; ++ci) {
    float2 r0 = xbuf[ci & 1][0], r1 = xbuf[ci & 1][1], r2 = xbuf[ci & 1][2];
    if (ci + 2 < 16) load_ch(ci + 2, xbuf[ci & 1]);
    float xv[9];
    xv[0] = wok * __shfl_up(r0.y, 1, 64); xv[1] = r0.x; xv[2] = r0.y;
    xv[3] = wok * __shfl_up(r1.y, 1, 64); xv[4] = r1.x; xv[5] = r1.y;
    xv[6] = wok * __shfl_up(r2.y, 1, 64); xv[7] = r2.x; xv[8] = r2.y;
    const float* __restrict__ wrow = w2c + (size_t)(c_base + ci) * FB_WSTRIDE;
#pragma unroll
    for (int m = 0; m < KK; ++m) {
      float a = acc[m];
#pragma unroll
      for (int t = 0; t < 9; ++t) a += wrow[m * 9 + t] * xv[t];
      acc[m] = a;
    }
  }
  float2 g[2][5];
  auto load_g = [&](int ci, float2* dst) {
    const float* xc = xb + (size_t)(c_base + ci) * (HN * WN);
#pragma unroll
    for (int i = 0; i < 5; ++i) {
      int r = 2 * ho - 2 + i;
      dst[i] = (r >= 0 && r < HN) ? *(const float2*)(xc + r * WN + col)
                                  : make_float2(0.f, 0.f);
    }
  };
  load_g(0, g[0]);
  load_g(1, g[1]);
  if (wv >= 8) {
#pragma unroll
    for (int m = 0; m < KK; ++m) red[((wv - 8) * KK + m) * 64 + wo] = acc[m];
  }
  __syncthreads();
  if (wv < 8) {
#pragma unroll
    for (int m = 0; m < KK; ++m) red[(wv * KK + m) * 64 + wo] += acc[m];
  }
  __syncthreads();
  if (wv < 4) {
#pragma unroll
    for (int m = 0; m < KK; ++m)
      red[(wv * KK + m) * 64 + wo] += red[((wv + 4) * KK + m) * 64 + wo];
  }
  __syncthreads();
  if (wv < 2) {
#pragma unroll
    for (int m = 0; m < KK; ++m)
      red[(wv * KK + m) * 64 + wo] += red[((wv + 2) * KK + m) * 64 + wo];
  }
  __syncthreads();
  if (tid < 64) {
    const float vr0 = (ho > 0) ? 1.f : 0.f;
    const float vq0 = (wo > 0) ? 1.f : 0.f;
    float logit[KK];
    float mx = -1e30f;
#pragma unroll
    for (int m = 0; m < KK; ++m) {
      const float* t9 = tb + m * 9;
      float l = b2[m]
              + vr0 * (vq0 * t9[0] + t9[1] + t9[2])
              +       (vq0 * t9[3] + t9[4] + t9[5])
              +       (vq0 * t9[6] + t9[7] + t9[8]);
      l += red[(0 * KK + m) * 64 + wo] + red[(1 * KK + m) * 64 + wo];
      logit[m] = l;
      mx = fmaxf(mx, l);
    }
    float s = 0.f;
#pragma unroll
    for (int m = 0; m < KK; ++m) {
      float e = __expf(logit[m] - mx);
      logit[m] = e;
      s += e;
    }
    float inv = 1.f / s;
#pragma unroll
    for (int m = 0; m < KK; ++m) sm[m * 64 + wo] = logit[m] * inv;
  }
  __syncthreads();
  float smr[KK];
#pragma unroll
  for (int m = 0; m < KK; ++m) smr[m] = sm[m * 64 + wo];
  const float w63 = (wo < 63) ? 1.f : 0.f;
  for (int ci = 0; ci < 16; ++ci) {
    float2 v[5];
#pragma unroll
    for (int i = 0; i < 5; ++i) v[i] = g[ci & 1][i];
    if (ci + 2 < 16) load_g(ci + 2, g[ci & 1]);
    float acc2 = 0.f;
#pragma unroll
    for (int i = 0; i < 5; ++i) {
      float lx = wok * __shfl_up(v[i].x, 1, 64);
      float ly = wok * __shfl_up(v[i].y, 1, 64);
      float rx = w63 * __shfl_down(v[i].x, 1, 64);
      acc2 += lx * smr[i * 5 + 0] + ly * smr[i * 5 + 1]
            + v[i].x * smr[i * 5 + 2] + v[i].y * smr[i * 5 + 3]
            + rx * smr[i * 5 + 4];
    }
    out[(((size_t)(b * CN + c_base + ci)) * HO + ho) * WO + wo] = acc2;
  }
}

// ---------------------------------------------------------------------------
extern "C" void kernel_launch(void* const* d_in, const int* in_sizes, int n_in,
                              void* d_out, int out_size, void* d_ws, size_t ws_size,
                              hipStream_t stream) {
  const float* x  = (const float*)d_in[0];
  const float* w1 = (const float*)d_in[1];
  const float* b1 = (const float*)d_in[2];
  const float* w2 = (const float*)d_in[3];
  const float* b2 = (const float*)d_in[4];
  float* out = (float*)d_out;
  float* ws  = (float*)d_ws;

  if (ws_size >= WS_NEED) {
    float* pl = ws + PL_OFF;
    float* sm = ws + SM_OFF;
    hipLaunchKernelGGL(compose_mfma, dim3(9, 16), dim3(64), 0, stream,
                       w1, b1, w2, ws);
    hipLaunchKernelGGL(transpose_x, dim3(8, HN, BN), dim3(256), 0, stream,
                       x, ws);
    hipLaunchKernelGGL(conv_mfma, dim3(16, HO, BN), dim3(64), 0, stream,
                       ws, pl);
    hipLaunchKernelGGL(softmax_kernel, dim3(HO, BN), dim3(64), 0, stream,
                       b2, ws + TB_OFF, pl, sm);
    hipLaunchKernelGGL(gather_kernel, dim3(HO, BN, 4), dim3(512), 0, stream,
                       x, sm, out);
  } else {
    hipLaunchKernelGGL(compose_w_fb, dim3(225), dim3(256), 0, stream,
                       w1, b1, w2, ws);
    hipLaunchKernelGGL(fused_fb, dim3(HO, BN), dim3(1024), 0, stream,
                       x, b2, ws, out);
  }
}

// Round 7
// 174.094 us; speedup vs baseline: 1.2323x; 1.2323x over previous
//
#include <hip/hip_runtime.h>
#include <math.h>

// Problem constants
#define BN   4
#define CN   256
#define HN   128
#define WN   128
#define COMP 64
#define KK   25      // K*K taps
#define HO   64
#define WO   64
#define NZC  8       // K-splits for MFMA conv (32 ch each)

// ---------------- fast-path workspace layout (float offsets) ----------------
// wA : 9*16*64*8 bf16 A-fragments = 36864 floats
// tb : 225 floats (+pad to 256)
// pl : NZC * BN*HO*KK*64 partial logits
// sm : BN*HO*KK*64 softmaxed mask
// xT : BN*HN*WN*CN bf16 (NHWC) = 8388608 float-slots
#define TB_OFF    36864
#define PL_OFF    37120
#define PL_SLICE  (BN * HO * KK * 64)              // 409600
#define SM_OFF    (PL_OFF + NZC * PL_SLICE)        // 3313920
#define XT_OFF    (SM_OFF + PL_SLICE)              // 3723520
#define WS_NEED   ((size_t)(XT_OFF + (size_t)BN * HN * WN * CN / 2) * 4)

typedef short v8s  __attribute__((ext_vector_type(8)));
typedef float v16f __attribute__((ext_vector_type(16)));

__device__ inline ushort f2bf(float f) {       // fp32 -> bf16 bits, RNE
  unsigned u = __float_as_uint(f);
  return (ushort)((u + 0x7fffu + ((u >> 16) & 1u)) >> 16);
}

// ---------------------------------------------------------------------------
// Compose: bake w2*w1 into MFMA A-fragment order (bf16) + tb.
// Grid (9 taps, 16 chunks), 64 threads. m=lane&31, half=lane>>5.
// wA[((t*16+chunk)*64+lane)*8 + j] = W_t[c = chunk*16+half*8+j][m]  (m<25)
// ---------------------------------------------------------------------------
__global__ __launch_bounds__(64) void compose_mfma(
    const float* __restrict__ w1, const float* __restrict__ b1,
    const float* __restrict__ w2, float* __restrict__ ws) {
  const int t = blockIdx.x, chunk = blockIdx.y;
  const int lane = threadIdx.x;
  const int m = lane & 31, half = lane >> 5;
  const int c0 = chunk * 16 + half * 8;
  float acc[8] = {0.f, 0.f, 0.f, 0.f, 0.f, 0.f, 0.f, 0.f};
  if (m < KK) {
    for (int k = 0; k < COMP; ++k) {
      float wv = w2[(size_t)(m * COMP + k) * 9 + t];
      const float* w1r = w1 + (size_t)k * CN + c0;
      float4 a = *(const float4*)w1r;
      float4 bq = *(const float4*)(w1r + 4);
      acc[0] += wv * a.x;  acc[1] += wv * a.y;
      acc[2] += wv * a.z;  acc[3] += wv * a.w;
      acc[4] += wv * bq.x; acc[5] += wv * bq.y;
      acc[6] += wv * bq.z; acc[7] += wv * bq.w;
    }
  }
  ushort* wA = (ushort*)ws;
  ushort pk[8];
#pragma unroll
  for (int j = 0; j < 8; ++j) pk[j] = f2bf(acc[j]);
  *(ushort4*)(wA + ((size_t)(t * 16 + chunk) * 64 + lane) * 8) =
      make_ushort4(pk[0], pk[1], pk[2], pk[3]);
  *(ushort4*)(wA + ((size_t)(t * 16 + chunk) * 64 + lane) * 8 + 4) =
      make_ushort4(pk[4], pk[5], pk[6], pk[7]);
  if (chunk == 0 && lane < KK) {
    float tbv = 0.f;
    for (int k = 0; k < COMP; ++k)
      tbv += w2[(size_t)(lane * COMP + k) * 9 + t] * b1[k];
    ws[TB_OFF + lane * 9 + t] = tbv;
  }
}

// ---------------------------------------------------------------------------
// Transpose x NCHW fp32 -> xT NHWC bf16. Grid (8, HN, BN), 256 threads.
// ---------------------------------------------------------------------------
__global__ __launch_bounds__(256) void transpose_x(
    const float* __restrict__ x, float* __restrict__ ws) {
  __shared__ float st[64][65];
  const int wt = blockIdx.x & 1, ct = blockIdx.x >> 1;
  const int h = blockIdx.y, b = blockIdx.z;
  const int tid = threadIdx.x;
  const int w0 = wt * 64, c0 = ct * 64;
  {
    const int wl = tid & 63, cw = tid >> 6;
#pragma unroll
    for (int i = 0; i < 16; ++i) {
      int cl = cw * 16 + i;
      st[cl][wl] = x[((size_t)(b * CN + c0 + cl) * HN + h) * WN + w0 + wl];
    }
  }
  __syncthreads();
  ushort* xT = (ushort*)(ws + XT_OFF);
  const int cg = tid & 15, wl0 = tid >> 4;
#pragma unroll
  for (int wi = 0; wi < 4; ++wi) {
    int wl = wl0 + wi * 16;
    ushort4 o = make_ushort4(f2bf(st[cg * 4 + 0][wl]), f2bf(st[cg * 4 + 1][wl]),
                             f2bf(st[cg * 4 + 2][wl]), f2bf(st[cg * 4 + 3][wl]));
    *(ushort4*)(xT + ((size_t)((b * HN + h) * WN + w0 + wl)) * CN + c0 + cg * 4) = o;
  }
}

// ---------------------------------------------------------------------------
// MFMA conv: 9 tap-GEMMs, 32(m) x 32(px) per wave, K=32 channels (z-slice).
// Grid (16 = wt|z<<1, HO, BN) = 4096 one-wave blocks -> 16 waves/CU.
// C/D layout: col(px)=lane&31, row(m)=(reg&3)+8*(reg>>2)+4*(lane>>5).
// ---------------------------------------------------------------------------
__global__ __launch_bounds__(64) void conv_mfma(
    const float* __restrict__ ws, float* __restrict__ pl) {
  const int wt = blockIdx.x & 1, z = blockIdx.x >> 1;   // z 0..7
  const int ho = blockIdx.y, b = blockIdx.z;
  const int lane = threadIdx.x;
  const int n = lane & 31, half = lane >> 5;
  const int wo = wt * 32 + n;
  const ushort* xT = (const ushort*)(ws + XT_OFF);
  const ushort* wA = (const ushort*)ws;
  const int coff = z * 32 + half * 8;
  const v8s zero8 = {};
  v16f acc = {};

#pragma unroll
  for (int dr = 0; dr < 3; ++dr) {
    const int r = 2 * ho + dr - 1;
    if (r < 0) continue;                       // wave-uniform (ho==0, dr==0)
#pragma unroll
    for (int dc = 0; dc < 3; ++dc) {
      const int t = dr * 3 + dc;
      const int q = 2 * wo + dc - 1;
      const bool bad = q < 0;                  // only lane wo==0, dc==0
      const int qc = bad ? 0 : q;
      const ushort* bp = xT + ((size_t)((b * HN + r) * WN + qc)) * CN + coff;
      const ushort* ap = wA + ((size_t)(t * 16 + z * 2) * 64 + lane) * 8;
      v8s bf0 = *(const v8s*)bp;
      v8s bf1 = *(const v8s*)(bp + 16);
      v8s af0 = *(const v8s*)ap;
      v8s af1 = *(const v8s*)(ap + 512);
      if (dc == 0 && bad) { bf0 = zero8; bf1 = zero8; }
      acc = __builtin_amdgcn_mfma_f32_32x32x16_bf16(af0, bf0, acc, 0, 0, 0);
      acc = __builtin_amdgcn_mfma_f32_32x32x16_bf16(af1, bf1, acc, 0, 0, 0);
    }
  }

  float* dst = pl + (size_t)z * PL_SLICE + ((size_t)(b * HO + ho) * KK) * 64 + wo;
#pragma unroll
  for (int rg = 0; rg < 16; ++rg) {
    int m = (rg & 3) + 8 * (rg >> 2) + 4 * half;
    if (m < KK) dst[(size_t)m * 64] = acc[rg];
  }
}

// ---------------------------------------------------------------------------
// Softmax: parallel 8-slice reduction + softmax(25).
// Grid (HO, BN), 512 threads = 8 waves; wave s owns pl slice s; lane = wo.
// 25 independent coalesced loads per lane (batched under one vmcnt wait),
// LDS tree 8->4->2->1, wave 0 adds bias/border terms, softmax, writes sm.
// ---------------------------------------------------------------------------
__global__ __launch_bounds__(512) void softmax_kernel(
    const float* __restrict__ b2, const float* __restrict__ tb,
    const float* __restrict__ pl, float* __restrict__ sm) {
  const int ho = blockIdx.x, b = blockIdx.y;
  const int tid = threadIdx.x;
  const int wo = tid & 63;
  const int wv = tid >> 6;                     // 0..7 = slice
  __shared__ float red[8 * KK * 64];           // 51200 B

  // load this wave's slice: 25 independent loads into an array first
  float v[KK];
  {
    const float* base = pl + (size_t)wv * PL_SLICE +
                        ((size_t)(b * HO + ho) * KK) * 64 + wo;
#pragma unroll
    for (int m = 0; m < KK; ++m) v[m] = base[(size_t)m * 64];
  }
#pragma unroll
  for (int m = 0; m < KK; ++m) red[(wv * KK + m) * 64 + wo] = v[m];
  __syncthreads();
  if (wv < 4) {
#pragma unroll
    for (int m = 0; m < KK; ++m)
      red[(wv * KK + m) * 64 + wo] += red[((wv + 4) * KK + m) * 64 + wo];
  }
  __syncthreads();
  if (wv < 2) {
#pragma unroll
    for (int m = 0; m < KK; ++m)
      red[(wv * KK + m) * 64 + wo] += red[((wv + 2) * KK + m) * 64 + wo];
  }
  __syncthreads();
  if (tid < 64) {
    const float vr0 = (ho > 0) ? 1.f : 0.f;
    const float vq0 = (wo > 0) ? 1.f : 0.f;
    float logit[KK];
    float mx = -1e30f;
#pragma unroll
    for (int m = 0; m < KK; ++m) {
      const float* t9 = tb + m * 9;
      float l = b2[m]
              + vr0 * (vq0 * t9[0] + t9[1] + t9[2])
              +       (vq0 * t9[3] + t9[4] + t9[5])
              +       (vq0 * t9[6] + t9[7] + t9[8]);
      l += red[(0 * KK + m) * 64 + wo] + red[(1 * KK + m) * 64 + wo];
      logit[m] = l;
      mx = fmaxf(mx, l);
    }
    float ssum = 0.f;
#pragma unroll
    for (int m = 0; m < KK; ++m) {
      float e = __expf(logit[m] - mx);
      logit[m] = e;
      ssum += e;
    }
    float inv = 1.f / ssum;
    float* dst = sm + ((size_t)(b * HO + ho) * KK) * 64 + wo;
#pragma unroll
    for (int m = 0; m < KK; ++m) dst[(size_t)m * 64] = logit[m] * inv;
  }
}

// ---------------------------------------------------------------------------
// CARAFE gather: barrier-free, LDS-free. Grid (HO, BN, 4), 512 threads.
// Wave wv owns 8 channels (c = z*64 + wv*8 + ci); lane = wo.
// Mask in registers (25 coalesced loads); x via float2 + shuffles.
// ---------------------------------------------------------------------------
__global__ __launch_bounds__(512) void gather_kernel(
    const float* __restrict__ x, const float* __restrict__ sm,
    float* __restrict__ out) {
  const int ho  = blockIdx.x;
  const int b   = blockIdx.y;
  const int z   = blockIdx.z;
  const int tid = threadIdx.x;
  const int wo  = tid & 63;
  const int wv  = tid >> 6;                    // 0..7
  const int c_base = __builtin_amdgcn_readfirstlane(z * 64 + wv * 8);

  float smr[KK];
  {
    const float* smp = sm + ((size_t)(b * HO + ho) * KK) * 64 + wo;
#pragma unroll
    for (int m = 0; m < KK; ++m) smr[m] = smp[(size_t)m * 64];
  }

  const float* __restrict__ xb = x + (size_t)(b * CN) * (HN * WN);
  const int col = 2 * wo;
  const float wok = (wo > 0) ? 1.f : 0.f;
  const float w63 = (wo < 63) ? 1.f : 0.f;

  float2 g[2][5];
  auto load_g = [&](int ci, float2* dst) {
    const float* xc = xb + (size_t)(c_base + ci) * (HN * WN);
#pragma unroll
    for (int i = 0; i < 5; ++i) {
      int r = 2 * ho - 2 + i;
      dst[i] = (r >= 0 && r < HN) ? *(const float2*)(xc + r * WN + col)
                                  : make_float2(0.f, 0.f);
    }
  };
  load_g(0, g[0]);
  load_g(1, g[1]);

  for (int ci = 0; ci < 8; ++ci) {
    float2 v[5];
#pragma unroll
    for (int i = 0; i < 5; ++i) v[i] = g[ci & 1][i];
    if (ci + 2 < 8) load_g(ci + 2, g[ci & 1]);

    float acc2 = 0.f;
#pragma unroll
    for (int i = 0; i < 5; ++i) {
      float lx = wok * __shfl_up(v[i].x, 1, 64);    // col 2wo-2
      float ly = wok * __shfl_up(v[i].y, 1, 64);    // col 2wo-1
      float rx = w63 * __shfl_down(v[i].x, 1, 64);  // col 2wo+2
      acc2 += lx * smr[i * 5 + 0] + ly * smr[i * 5 + 1]
            + v[i].x * smr[i * 5 + 2] + v[i].y * smr[i * 5 + 3]
            + rx * smr[i * 5 + 4];
    }
    out[(((size_t)(b * CN + c_base + ci)) * HO + ho) * WO + wo] = acc2;
  }
}

// ============================ FALLBACK PATH ================================
// Round-2 proven kernels (used only if ws_size < WS_NEED).
#define FB_WSTRIDE 240
#define FB_TB_OFF  (256 * FB_WSTRIDE)

__global__ __launch_bounds__(256) void compose_w_fb(
    const float* __restrict__ w1, const float* __restrict__ b1,
    const float* __restrict__ w2, float* __restrict__ ws) {
  int mt = blockIdx.x, c = threadIdx.x;
  float acc = 0.f;
#pragma unroll 8
  for (int k = 0; k < COMP; ++k)
    acc += w2[(size_t)(mt / 9 * COMP + k) * 9 + (mt % 9)] * w1[k * CN + c];
  ws[c * FB_WSTRIDE + mt] = acc;
  if (mt < FB_WSTRIDE - 225) ws[c * FB_WSTRIDE + 225 + mt] = 0.f;
  if (c == 0) {
    float tbv = 0.f;
    for (int k = 0; k < COMP; ++k)
      tbv += w2[(size_t)(mt / 9 * COMP + k) * 9 + (mt % 9)] * b1[k];
    ws[FB_TB_OFF + mt] = tbv;
  }
}

__global__ __launch_bounds__(1024, 4) void fused_fb(
    const float* __restrict__ x, const float* __restrict__ b2,
    const float* __restrict__ ws, float* __restrict__ out) {
  const int ho = blockIdx.x, b = blockIdx.y, tid = threadIdx.x;
  const int wo = tid & 63, wv = tid >> 6;
  const int c_base = __builtin_amdgcn_readfirstlane(wv * 16);
  const float* __restrict__ w2c = ws;
  const float* __restrict__ tb  = ws + FB_TB_OFF;
  __shared__ float red[8 * KK * 64];
  __shared__ float sm[KK * 64];
  const float* __restrict__ xb = x + (size_t)(b * CN) * (HN * WN);
  const int col = 2 * wo;
  float acc[KK];
#pragma unroll
  for (int m = 0; m < KK; ++m) acc[m] = 0.f;
  float2 xbuf[2][3];
  auto load_ch = [&](int ci, float2* dst) {
    const float* xc = xb + (size_t)(c_base + ci) * (HN * WN);
    dst[0] = (ho > 0) ? *(const float2*)(xc + (2 * ho - 1) * WN + col)
                      : make_float2(0.f, 0.f);
    dst[1] = *(const float2*)(xc + (2 * ho) * WN + col);
    dst[2] = *(const float2*)(xc + (2 * ho + 1) * WN + col);
  };
  load_ch(0, xbuf[0]);
  load_ch(1, xbuf[1]);
  const float wok = (wo > 0) ? 1.f : 0.f;
  for (int ci = 0; ci < 16; ++ci) {
    float2 r0 = xbuf[ci & 1][0], r1 = xbuf[ci & 1][1], r2 = xbuf[ci & 1][2];
    if (ci + 2 < 16) load_ch(ci + 2, xbuf[ci & 1]);
    float xv[9];
    xv[0] = wok * __shfl_up(r0.y, 1, 64); xv[1] = r0.x; xv[2] = r0.y;
    xv[3] = wok * __shfl_up(r1.y, 1, 64); xv[4] = r1.x; xv[5] = r1.y;
    xv[6] = wok * __shfl_up(r2.y, 1, 64); xv[7] = r2.x; xv[8] = r2.y;
    const float* __restrict__ wrow = w2c + (size_t)(c_base + ci) * FB_WSTRIDE;
#pragma unroll
    for (int m = 0; m < KK; ++m) {
      float a = acc[m];
#pragma unroll
      for (int t = 0; t < 9; ++t) a += wrow[m * 9 + t] * xv[t];
      acc[m] = a;
    }
  }
  float2 g[2][5];
  auto load_g = [&](int ci, float2* dst) {
    const float* xc = xb + (size_t)(c_base + ci) * (HN * WN);
#pragma unroll
    for (int i = 0; i < 5; ++i) {
      int r = 2 * ho - 2 + i;
      dst[i] = (r >= 0 && r < HN) ? *(const float2*)(xc + r * WN + col)
                                  : make_float2(0.f, 0.f);
    }
  };
  load_g(0, g[0]);
  load_g(1, g[1]);
  if (wv >= 8) {
#pragma unroll
    for (int m = 0; m < KK; ++m) red[((wv - 8) * KK + m) * 64 + wo] = acc[m];
  }
  __syncthreads();
  if (wv < 8) {
#pragma unroll
    for (int m = 0; m < KK; ++m) red[(wv * KK + m) * 64 + wo] += acc[m];
  }
  __syncthreads();
  if (wv < 4) {
#pragma unroll
    for (int m = 0; m < KK; ++m)
      red[(wv * KK + m) * 64 + wo] += red[((wv + 4) * KK + m) * 64 + wo];
  }
  __syncthreads();
  if (wv < 2) {
#pragma unroll
    for (int m = 0; m < KK; ++m)
      red[(wv * KK + m) * 64 + wo] += red[((wv + 2) * KK + m) * 64 + wo];
  }
  __syncthreads();
  if (tid < 64) {
    const float vr0 = (ho > 0) ? 1.f : 0.f;
    const float vq0 = (wo > 0) ? 1.f : 0.f;
    float logit[KK];
    float mx = -1e30f;
#pragma unroll
    for (int m = 0; m < KK; ++m) {
      const float* t9 = tb + m * 9;
      float l = b2[m]
              + vr0 * (vq0 * t9[0] + t9[1] + t9[2])
              +       (vq0 * t9[3] + t9[4] + t9[5])
              +       (vq0 * t9[6] + t9[7] + t9[8]);
      l += red[(0 * KK + m) * 64 + wo] + red[(1 * KK + m) * 64 + wo];
      logit[m] = l;
      mx = fmaxf(mx, l);
    }
    float s = 0.f;
#pragma unroll
    for (int m = 0; m < KK; ++m) {
      float e = __expf(logit[m] - mx);
      logit[m] = e;
      s += e;
    }
    float inv = 1.f / s;
#pragma unroll
    for (int m = 0; m < KK; ++m) sm[m * 64 + wo] = logit[m] * inv;
  }
  __syncthreads();
  float smr[KK];
#pragma unroll
  for (int m = 0; m < KK; ++m) smr[m] = sm[m * 64 + wo];
  const float w63 = (wo < 63) ? 1.f : 0.f;
  for (int ci = 0; ci < 16; ++ci) {
    float2 v[5];
#pragma unroll
    for (int i = 0; i < 5; ++i) v[i] = g[ci & 1][i];
    if (ci + 2 < 16) load_g(ci + 2, g[ci & 1]);
    float acc2 = 0.f;
#pragma unroll
    for (int i = 0; i < 5; ++i) {
      float lx = wok * __shfl_up(v[i].x, 1, 64);
      float ly = wok * __shfl_up(v[i].y, 1, 64);
      float rx = w63 * __shfl_down(v[i].x, 1, 64);
      acc2 += lx * smr[i * 5 + 0] + ly * smr[i * 5 + 1]
            + v[i].x * smr[i * 5 + 2] + v[i].y * smr[i * 5 + 3]
            + rx * smr[i * 5 + 4];
    }
    out[(((size_t)(b * CN + c_base + ci)) * HO + ho) * WO + wo] = acc2;
  }
}

// ---------------------------------------------------------------------------
extern "C" void kernel_launch(void* const* d_in, const int* in_sizes, int n_in,
                              void* d_out, int out_size, void* d_ws, size_t ws_size,
                              hipStream_t stream) {
  const float* x  = (const float*)d_in[0];
  const float* w1 = (const float*)d_in[1];
  const float* b1 = (const float*)d_in[2];
  const float* w2 = (const float*)d_in[3];
  const float* b2 = (const float*)d_in[4];
  float* out = (float*)d_out;
  float* ws  = (float*)d_ws;

  if (ws_size >= WS_NEED) {
    float* pl = ws + PL_OFF;
    float* sm = ws + SM_OFF;
    hipLaunchKernelGGL(compose_mfma, dim3(9, 16), dim3(64), 0, stream,
                       w1, b1, w2, ws);
    hipLaunchKernelGGL(transpose_x, dim3(8, HN, BN), dim3(256), 0, stream,
                       x, ws);
    hipLaunchKernelGGL(conv_mfma, dim3(16, HO, BN), dim3(64), 0, stream,
                       ws, pl);
    hipLaunchKernelGGL(softmax_kernel, dim3(HO, BN), dim3(512), 0, stream,
                       b2, ws + TB_OFF, pl, sm);
    hipLaunchKernelGGL(gather_kernel, dim3(HO, BN, 4), dim3(512), 0, stream,
                       x, sm, out);
  } else {
    hipLaunchKernelGGL(compose_w_fb, dim3(225), dim3(256), 0, stream,
                       w1, b1, w2, ws);
    hipLaunchKernelGGL(fused_fb, dim3(HO, BN), dim3(1024), 0, stream,
                       x, b2, ws, out);
  }
}

// Round 8
// 161.802 us; speedup vs baseline: 1.3259x; 1.0760x over previous
//
#include <hip/hip_runtime.h>
#include <math.h>

// Problem constants
#define BN   4
#define CN   256
#define HN   128
#define WN   128
#define COMP 64
#define KK   25      // K*K taps
#define HO   64
#define WO   64

// ---------------- fast-path workspace layout (float offsets) ----------------
// wA : 9*16*64*8 bf16 A-fragments = 36864 floats
// tb : 225 floats (+pad to 256)
// sm : BN*HO*KK*64 softmaxed mask = 409600 floats
// xT : BN*HN*WN*CN bf16 (NHWC) = 8388608 float-slots
#define TB_OFF    36864
#define SM_OFF    37120
#define SM_SLICE  (BN * HO * KK * 64)              // 409600
#define XT_OFF    (SM_OFF + SM_SLICE)              // 446720
#define WS_NEED   ((size_t)(XT_OFF + (size_t)BN * HN * WN * CN / 2) * 4)

typedef short v8s  __attribute__((ext_vector_type(8)));
typedef float v16f __attribute__((ext_vector_type(16)));

__device__ inline ushort f2bf(float f) {       // fp32 -> bf16 bits, RNE
  unsigned u = __float_as_uint(f);
  return (ushort)((u + 0x7fffu + ((u >> 16) & 1u)) >> 16);
}

// ---------------------------------------------------------------------------
// Prep kernel: blocks [0,4096) transpose x NCHW fp32 -> xT NHWC bf16;
// blocks [4096, 4132) compose wA (MFMA A-fragments, bf16) + tb.
// 256 threads. Branch is block-uniform.
// ---------------------------------------------------------------------------
__global__ __launch_bounds__(256) void prep_kernel(
    const float* __restrict__ x, const float* __restrict__ w1,
    const float* __restrict__ b1, const float* __restrict__ w2,
    float* __restrict__ ws) {
  const int bid = blockIdx.x;
  const int tid = threadIdx.x;
  if (bid < 4096) {
    // ---- transpose: 64x64 (c x w) tile via LDS ----
    __shared__ float st[64][65];
    const int b = bid >> 10, h = (bid >> 3) & 127, bx = bid & 7;
    const int wt = bx & 1, ct = bx >> 1;
    const int w0 = wt * 64, c0 = ct * 64;
    {
      const int wl = tid & 63, cw = tid >> 6;
#pragma unroll
      for (int i = 0; i < 16; ++i) {
        int cl = cw * 16 + i;
        st[cl][wl] = x[((size_t)(b * CN + c0 + cl) * HN + h) * WN + w0 + wl];
      }
    }
    __syncthreads();
    ushort* xT = (ushort*)(ws + XT_OFF);
    const int cg = tid & 15, wl0 = tid >> 4;
#pragma unroll
    for (int wi = 0; wi < 4; ++wi) {
      int wl = wl0 + wi * 16;
      ushort4 o = make_ushort4(f2bf(st[cg * 4 + 0][wl]), f2bf(st[cg * 4 + 1][wl]),
                               f2bf(st[cg * 4 + 2][wl]), f2bf(st[cg * 4 + 3][wl]));
      *(ushort4*)(xT + ((size_t)((b * HN + h) * WN + w0 + wl)) * CN + c0 + cg * 4) = o;
    }
  } else {
    // ---- compose: cid = (t, chunkgroup); 4 chunks per block ----
    const int cid = bid - 4096;                // 0..35
    const int t = cid >> 2;                    // 0..8
    const int chunk = (cid & 3) * 4 + (tid >> 6);  // 0..15
    const int lane = tid & 63;
    const int m = lane & 31, half = lane >> 5;
    const int c0 = chunk * 16 + half * 8;
    float acc[8] = {0.f, 0.f, 0.f, 0.f, 0.f, 0.f, 0.f, 0.f};
    if (m < KK) {
      for (int k = 0; k < COMP; ++k) {
        float wv = w2[(size_t)(m * COMP + k) * 9 + t];
        const float* w1r = w1 + (size_t)k * CN + c0;
        float4 a = *(const float4*)w1r;
        float4 bq = *(const float4*)(w1r + 4);
        acc[0] += wv * a.x;  acc[1] += wv * a.y;
        acc[2] += wv * a.z;  acc[3] += wv * a.w;
        acc[4] += wv * bq.x; acc[5] += wv * bq.y;
        acc[6] += wv * bq.z; acc[7] += wv * bq.w;
      }
    }
    ushort* wA = (ushort*)ws;
    ushort pk[8];
#pragma unroll
    for (int j = 0; j < 8; ++j) pk[j] = f2bf(acc[j]);
    *(ushort4*)(wA + ((size_t)(t * 16 + chunk) * 64 + lane) * 8) =
        make_ushort4(pk[0], pk[1], pk[2], pk[3]);
    *(ushort4*)(wA + ((size_t)(t * 16 + chunk) * 64 + lane) * 8 + 4) =
        make_ushort4(pk[4], pk[5], pk[6], pk[7]);
    if (chunk == 0 && lane < KK) {
      float tbv = 0.f;
      for (int k = 0; k < COMP; ++k)
        tbv += w2[(size_t)(lane * COMP + k) * 9 + t] * b1[k];
      ws[TB_OFF + lane * 9 + t] = tbv;
    }
  }
}

// ---------------------------------------------------------------------------
// Conv + softmax fused: grid (HO, BN) = 256 blocks, 512 threads = 8 waves.
// Wave wv owns K-slice z=wv (32 channels) and computes BOTH 32-px tiles
// (wt 0,1) of the 64-px row: 9 taps x (1 shared A-pair + 2 B-pairs) MFMAs.
// LDS tree 8->4->2->1 over slices, wave 0 adds bias/border, softmax, -> sm.
// C/D layout: col(px)=lane&31, row(m)=(reg&3)+8*(reg>>2)+4*(lane>>5).
// ---------------------------------------------------------------------------
__global__ __launch_bounds__(512) void conv_softmax(
    const float* __restrict__ ws, const float* __restrict__ b2,
    float* __restrict__ sm) {
  const int ho = blockIdx.x, b = blockIdx.y;
  const int tid = threadIdx.x;
  const int lane = tid & 63;
  const int z = tid >> 6;                      // 0..7 = K-slice
  const int n = lane & 31, half = lane >> 5;
  const ushort* xT = (const ushort*)(ws + XT_OFF);
  const ushort* wA = (const ushort*)ws;
  const int coff = z * 32 + half * 8;
  const v8s zero8 = {};
  v16f acc[2] = {{}, {}};

  __shared__ float red[8 * KK * 64];           // 51200 B

#pragma unroll
  for (int dr = 0; dr < 3; ++dr) {
    const int r = 2 * ho + dr - 1;
    if (r < 0) continue;                       // block-uniform (ho==0, dr==0)
#pragma unroll
    for (int dc = 0; dc < 3; ++dc) {
      const int t = dr * 3 + dc;
      const ushort* ap = wA + ((size_t)(t * 16 + z * 2) * 64 + lane) * 8;
      v8s af0 = *(const v8s*)ap;
      v8s af1 = *(const v8s*)(ap + 512);
      const size_t rowbase = (size_t)((b * HN + r) * WN);
#pragma unroll
      for (int wt = 0; wt < 2; ++wt) {
        const int wo = wt * 32 + n;
        const int q = 2 * wo + dc - 1;
        const bool bad = q < 0;                // only lane n==0, wt==0, dc==0
        const int qc = bad ? 0 : q;
        const ushort* bp = xT + (rowbase + qc) * CN + coff;
        v8s bf0 = *(const v8s*)bp;
        v8s bf1 = *(const v8s*)(bp + 16);
        if (dc == 0 && bad) { bf0 = zero8; bf1 = zero8; }
        acc[wt] = __builtin_amdgcn_mfma_f32_32x32x16_bf16(af0, bf0, acc[wt], 0, 0, 0);
        acc[wt] = __builtin_amdgcn_mfma_f32_32x32x16_bf16(af1, bf1, acc[wt], 0, 0, 0);
      }
    }
  }

  // scatter acc (m<25 rows) into red[z][m][px]
#pragma unroll
  for (int wt = 0; wt < 2; ++wt) {
#pragma unroll
    for (int rg = 0; rg < 16; ++rg) {
      int m = (rg & 3) + 8 * (rg >> 2) + 4 * half;
      if (m < KK) red[(z * KK + m) * 64 + wt * 32 + n] = acc[wt][rg];
    }
  }
  __syncthreads();
  {
    const int wv = z, wo = lane;
    if (wv < 4) {
#pragma unroll
      for (int m = 0; m < KK; ++m)
        red[(wv * KK + m) * 64 + wo] += red[((wv + 4) * KK + m) * 64 + wo];
    }
    __syncthreads();
    if (wv < 2) {
#pragma unroll
      for (int m = 0; m < KK; ++m)
        red[(wv * KK + m) * 64 + wo] += red[((wv + 2) * KK + m) * 64 + wo];
    }
    __syncthreads();
  }
  if (tid < 64) {
    const int wo = tid;
    const float* tb = ws + TB_OFF;
    const float vr0 = (ho > 0) ? 1.f : 0.f;
    const float vq0 = (wo > 0) ? 1.f : 0.f;
    float logit[KK];
    float mx = -1e30f;
#pragma unroll
    for (int m = 0; m < KK; ++m) {
      const float* t9 = tb + m * 9;
      float l = b2[m]
              + vr0 * (vq0 * t9[0] + t9[1] + t9[2])
              +       (vq0 * t9[3] + t9[4] + t9[5])
              +       (vq0 * t9[6] + t9[7] + t9[8]);
      l += red[(0 * KK + m) * 64 + wo] + red[(1 * KK + m) * 64 + wo];
      logit[m] = l;
      mx = fmaxf(mx, l);
    }
    float ssum = 0.f;
#pragma unroll
    for (int m = 0; m < KK; ++m) {
      float e = __expf(logit[m] - mx);
      logit[m] = e;
      ssum += e;
    }
    float inv = 1.f / ssum;
    float* dst = sm + ((size_t)(b * HO + ho) * KK) * 64 + wo;
#pragma unroll
    for (int m = 0; m < KK; ++m) dst[(size_t)m * 64] = logit[m] * inv;
  }
}

// ---------------------------------------------------------------------------
// CARAFE gather: barrier-free, LDS-free. Grid (HO, BN, 4), 512 threads.
// Wave wv owns 8 channels (c = z*64 + wv*8 + ci); lane = wo.
// Mask in registers (25 coalesced loads); x via float2 + shuffles.
// ---------------------------------------------------------------------------
__global__ __launch_bounds__(512) void gather_kernel(
    const float* __restrict__ x, const float* __restrict__ sm,
    float* __restrict__ out) {
  const int ho  = blockIdx.x;
  const int b   = blockIdx.y;
  const int z   = blockIdx.z;
  const int tid = threadIdx.x;
  const int wo  = tid & 63;
  const int wv  = tid >> 6;                    // 0..7
  const int c_base = __builtin_amdgcn_readfirstlane(z * 64 + wv * 8);

  float smr[KK];
  {
    const float* smp = sm + ((size_t)(b * HO + ho) * KK) * 64 + wo;
#pragma unroll
    for (int m = 0; m < KK; ++m) smr[m] = smp[(size_t)m * 64];
  }

  const float* __restrict__ xb = x + (size_t)(b * CN) * (HN * WN);
  const int col = 2 * wo;
  const float wok = (wo > 0) ? 1.f : 0.f;
  const float w63 = (wo < 63) ? 1.f : 0.f;

  float2 g[2][5];
  auto load_g = [&](int ci, float2* dst) {
    const float* xc = xb + (size_t)(c_base + ci) * (HN * WN);
#pragma unroll
    for (int i = 0; i < 5; ++i) {
      int r = 2 * ho - 2 + i;
      dst[i] = (r >= 0 && r < HN) ? *(const float2*)(xc + r * WN + col)
                                  : make_float2(0.f, 0.f);
    }
  };
  load_g(0, g[0]);
  load_g(1, g[1]);

  for (int ci = 0; ci < 8; ++ci) {
    float2 v[5];
#pragma unroll
    for (int i = 0; i < 5; ++i) v[i] = g[ci & 1][i];
    if (ci + 2 < 8) load_g(ci + 2, g[ci & 1]);

    float acc2 = 0.f;
#pragma unroll
    for (int i = 0; i < 5; ++i) {
      float lx = wok * __shfl_up(v[i].x, 1, 64);    // col 2wo-2
      float ly = wok * __shfl_up(v[i].y, 1, 64);    // col 2wo-1
      float rx = w63 * __shfl_down(v[i].x, 1, 64);  // col 2wo+2
      acc2 += lx * smr[i * 5 + 0] + ly * smr[i * 5 + 1]
            + v[i].x * smr[i * 5 + 2] + v[i].y * smr[i * 5 + 3]
            + rx * smr[i * 5 + 4];
    }
    out[(((size_t)(b * CN + c_base + ci)) * HO + ho) * WO + wo] = acc2;
  }
}

// ============================ FALLBACK PATH ================================
// Round-2 proven kernels (used only if ws_size < WS_NEED).
#define FB_WSTRIDE 240
#define FB_TB_OFF  (256 * FB_WSTRIDE)

__global__ __launch_bounds__(256) void compose_w_fb(
    const float* __restrict__ w1, const float* __restrict__ b1,
    const float* __restrict__ w2, float* __restrict__ ws) {
  int mt = blockIdx.x, c = threadIdx.x;
  float acc = 0.f;
#pragma unroll 8
  for (int k = 0; k < COMP; ++k)
    acc += w2[(size_t)(mt / 9 * COMP + k) * 9 + (mt % 9)] * w1[k * CN + c];
  ws[c * FB_WSTRIDE + mt] = acc;
  if (mt < FB_WSTRIDE - 225) ws[c * FB_WSTRIDE + 225 + mt] = 0.f;
  if (c == 0) {
    float tbv = 0.f;
    for (int k = 0; k < COMP; ++k)
      tbv += w2[(size_t)(mt / 9 * COMP + k) * 9 + (mt % 9)] * b1[k];
    ws[FB_TB_OFF + mt] = tbv;
  }
}

__global__ __launch_bounds__(1024, 4) void fused_fb(
    const float* __restrict__ x, const float* __restrict__ b2,
    const float* __restrict__ ws, float* __restrict__ out) {
  const int ho = blockIdx.x, b = blockIdx.y, tid = threadIdx.x;
  const int wo = tid & 63, wv = tid >> 6;
  const int c_base = __builtin_amdgcn_readfirstlane(wv * 16);
  const float* __restrict__ w2c = ws;
  const float* __restrict__ tb  = ws + FB_TB_OFF;
  __shared__ float red[8 * KK * 64];
  __shared__ float sm[KK * 64];
  const float* __restrict__ xb = x + (size_t)(b * CN) * (HN * WN);
  const int col = 2 * wo;
  float acc[KK];
#pragma unroll
  for (int m = 0; m < KK; ++m) acc[m] = 0.f;
  float2 xbuf[2][3];
  auto load_ch = [&](int ci, float2* dst) {
    const float* xc = xb + (size_t)(c_base + ci) * (HN * WN);
    dst[0] = (ho > 0) ? *(const float2*)(xc + (2 * ho - 1) * WN + col)
                      : make_float2(0.f, 0.f);
    dst[1] = *(const float2*)(xc + (2 * ho) * WN + col);
    dst[2] = *(const float2*)(xc + (2 * ho + 1) * WN + col);
  };
  load_ch(0, xbuf[0]);
  load_ch(1, xbuf[1]);
  const float wok = (wo > 0) ? 1.f : 0.f;
  for (int ci = 0; ci < 16; ++ci) {
    float2 r0 = xbuf[ci & 1][0], r1 = xbuf[ci & 1][1], r2 = xbuf[ci & 1][2];
    if (ci + 2 < 16) load_ch(ci + 2, xbuf[ci & 1]);
    float xv[9];
    xv[0] = wok * __shfl_up(r0.y, 1, 64); xv[1] = r0.x; xv[2] = r0.y;
    xv[3] = wok * __shfl_up(r1.y, 1, 64); xv[4] = r1.x; xv[5] = r1.y;
    xv[6] = wok * __shfl_up(r2.y, 1, 64); xv[7] = r2.x; xv[8] = r2.y;
    const float* __restrict__ wrow = w2c + (size_t)(c_base + ci) * FB_WSTRIDE;
#pragma unroll
    for (int m = 0; m < KK; ++m) {
      float a = acc[m];
#pragma unroll
      for (int t = 0; t < 9; ++t) a += wrow[m * 9 + t] * xv[t];
      acc[m] = a;
    }
  }
  float2 g[2][5];
  auto load_g = [&](int ci, float2* dst) {
    const float* xc = xb + (size_t)(c_base + ci) * (HN * WN);
#pragma unroll
    for (int i = 0; i < 5; ++i) {
      int r = 2 * ho - 2 + i;
      dst[i] = (r >= 0 && r < HN) ? *(const float2*)(xc + r * WN + col)
                                  : make_float2(0.f, 0.f);
    }
  };
  load_g(0, g[0]);
  load_g(1, g[1]);
  if (wv >= 8) {
#pragma unroll
    for (int m = 0; m < KK; ++m) red[((wv - 8) * KK + m) * 64 + wo] = acc[m];
  }
  __syncthreads();
  if (wv < 8) {
#pragma unroll
    for (int m = 0; m < KK; ++m) red[(wv * KK + m) * 64 + wo] += acc[m];
  }
  __syncthreads();
  if (wv < 4) {
#pragma unroll
    for (int m = 0; m < KK; ++m)
      red[(wv * KK + m) * 64 + wo] += red[((wv + 4) * KK + m) * 64 + wo];
  }
  __syncthreads();
  if (wv < 2) {
#pragma unroll
    for (int m = 0; m < KK; ++m)
      red[(wv * KK + m) * 64 + wo] += red[((wv + 2) * KK + m) * 64 + wo];
  }
  __syncthreads();
  if (tid < 64) {
    const float vr0 = (ho > 0) ? 1.f : 0.f;
    const float vq0 = (wo > 0) ? 1.f : 0.f;
    float logit[KK];
    float mx = -1e30f;
#pragma unroll
    for (int m = 0; m < KK; ++m) {
      const float* t9 = tb + m * 9;
      float l = b2[m]
              + vr0 * (vq0 * t9[0] + t9[1] + t9[2])
              +       (vq0 * t9[3] + t9[4] + t9[5])
              +       (vq0 * t9[6] + t9[7] + t9[8]);
      l += red[(0 * KK + m) * 64 + wo] + red[(1 * KK + m) * 64 + wo];
      logit[m] = l;
      mx = fmaxf(mx, l);
    }
    float s = 0.f;
#pragma unroll
    for (int m = 0; m < KK; ++m) {
      float e = __expf(logit[m] - mx);
      logit[m] = e;
      s += e;
    }
    float inv = 1.f / s;
#pragma unroll
    for (int m = 0; m < KK; ++m) sm[m * 64 + wo] = logit[m] * inv;
  }
  __syncthreads();
  float smr[KK];
#pragma unroll
  for (int m = 0; m < KK; ++m) smr[m] = sm[m * 64 + wo];
  const float w63 = (wo < 63) ? 1.f : 0.f;
  for (int ci = 0; ci < 16; ++ci) {
    float2 v[5];
#pragma unroll
    for (int i = 0; i < 5; ++i) v[i] = g[ci & 1][i];
    if (ci + 2 < 16) load_g(ci + 2, g[ci & 1]);
    float acc2 = 0.f;
#pragma unroll
    for (int i = 0; i < 5; ++i) {
      float lx = wok * __shfl_up(v[i].x, 1, 64);
      float ly = wok * __shfl_up(v[i].y, 1, 64);
      float rx = w63 * __shfl_down(v[i].x, 1, 64);
      acc2 += lx * smr[i * 5 + 0] + ly * smr[i * 5 + 1]
            + v[i].x * smr[i * 5 + 2] + v[i].y * smr[i * 5 + 3]
            + rx * smr[i * 5 + 4];
    }
    out[(((size_t)(b * CN + c_base + ci)) * HO + ho) * WO + wo] = acc2;
  }
}

// ---------------------------------------------------------------------------
extern "C" void kernel_launch(void* const* d_in, const int* in_sizes, int n_in,
                              void* d_out, int out_size, void* d_ws, size_t ws_size,
                              hipStream_t stream) {
  const float* x  = (const float*)d_in[0];
  const float* w1 = (const float*)d_in[1];
  const float* b1 = (const float*)d_in[2];
  const float* w2 = (const float*)d_in[3];
  const float* b2 = (const float*)d_in[4];
  float* out = (float*)d_out;
  float* ws  = (float*)d_ws;

  if (ws_size >= WS_NEED) {
    float* sm = ws + SM_OFF;
    hipLaunchKernelGGL(prep_kernel, dim3(4096 + 36), dim3(256), 0, stream,
                       x, w1, b1, w2, ws);
    hipLaunchKernelGGL(conv_softmax, dim3(HO, BN), dim3(512), 0, stream,
                       ws, b2, sm);
    hipLaunchKernelGGL(gather_kernel, dim3(HO, BN, 4), dim3(512), 0, stream,
                       x, sm, out);
  } else {
    hipLaunchKernelGGL(compose_w_fb, dim3(225), dim3(256), 0, stream,
                       w1, b1, w2, ws);
    hipLaunchKernelGGL(fused_fb, dim3(HO, BN), dim3(1024), 0, stream,
                       x, b2, ws, out);
  }
}

// Round 9
// 159.913 us; speedup vs baseline: 1.3415x; 1.0118x over previous
//
#include <hip/hip_runtime.h>
#include <math.h>

// Problem constants
#define BN   4
#define CN   256
#define HN   128
#define WN   128
#define COMP 64
#define KK   25      // K*K taps
#define HO   64
#define WO   64

// ---------------- fast-path workspace layout (float offsets) ----------------
// wA : 9*16*64*8 bf16 A-fragments = 36864 floats
// tb : 225 floats (+pad to 256)
// xT : BN*HN*WN*CN bf16 (NHWC) = 8388608 float-slots
#define TB_OFF    36864
#define XT_OFF    37120
#define WS_NEED   ((size_t)(XT_OFF + (size_t)BN * HN * WN * CN / 2) * 4)

typedef short v8s  __attribute__((ext_vector_type(8)));
typedef float v16f __attribute__((ext_vector_type(16)));

__device__ inline ushort f2bf(float f) {       // fp32 -> bf16 bits, RNE
  unsigned u = __float_as_uint(f);
  return (ushort)((u + 0x7fffu + ((u >> 16) & 1u)) >> 16);
}

// ---------------------------------------------------------------------------
// Prep kernel: blocks [0,4096) transpose x NCHW fp32 -> xT NHWC bf16;
// blocks [4096, 4132) compose wA (MFMA A-fragments, bf16) + tb.
// 256 threads. Branch is block-uniform.
// ---------------------------------------------------------------------------
__global__ __launch_bounds__(256) void prep_kernel(
    const float* __restrict__ x, const float* __restrict__ w1,
    const float* __restrict__ b1, const float* __restrict__ w2,
    float* __restrict__ ws) {
  const int bid = blockIdx.x;
  const int tid = threadIdx.x;
  if (bid < 4096) {
    // ---- transpose: 64x64 (c x w) tile via LDS ----
    __shared__ float st[64][65];
    const int b = bid >> 10, h = (bid >> 3) & 127, bx = bid & 7;
    const int wt = bx & 1, ct = bx >> 1;
    const int w0 = wt * 64, c0 = ct * 64;
    {
      const int wl = tid & 63, cw = tid >> 6;
#pragma unroll
      for (int i = 0; i < 16; ++i) {
        int cl = cw * 16 + i;
        st[cl][wl] = x[((size_t)(b * CN + c0 + cl) * HN + h) * WN + w0 + wl];
      }
    }
    __syncthreads();
    ushort* xT = (ushort*)(ws + XT_OFF);
    const int cg = tid & 15, wl0 = tid >> 4;
#pragma unroll
    for (int wi = 0; wi < 4; ++wi) {
      int wl = wl0 + wi * 16;
      ushort4 o = make_ushort4(f2bf(st[cg * 4 + 0][wl]), f2bf(st[cg * 4 + 1][wl]),
                               f2bf(st[cg * 4 + 2][wl]), f2bf(st[cg * 4 + 3][wl]));
      *(ushort4*)(xT + ((size_t)((b * HN + h) * WN + w0 + wl)) * CN + c0 + cg * 4) = o;
    }
  } else {
    // ---- compose: cid = (t, chunkgroup); 4 chunks per block ----
    const int cid = bid - 4096;                // 0..35
    const int t = cid >> 2;                    // 0..8
    const int chunk = (cid & 3) * 4 + (tid >> 6);  // 0..15
    const int lane = tid & 63;
    const int m = lane & 31, half = lane >> 5;
    const int c0 = chunk * 16 + half * 8;
    float acc[8] = {0.f, 0.f, 0.f, 0.f, 0.f, 0.f, 0.f, 0.f};
    if (m < KK) {
      for (int k = 0; k < COMP; ++k) {
        float wv = w2[(size_t)(m * COMP + k) * 9 + t];
        const float* w1r = w1 + (size_t)k * CN + c0;
        float4 a = *(const float4*)w1r;
        float4 bq = *(const float4*)(w1r + 4);
        acc[0] += wv * a.x;  acc[1] += wv * a.y;
        acc[2] += wv * a.z;  acc[3] += wv * a.w;
        acc[4] += wv * bq.x; acc[5] += wv * bq.y;
        acc[6] += wv * bq.z; acc[7] += wv * bq.w;
      }
    }
    ushort* wA = (ushort*)ws;
    ushort pk[8];
#pragma unroll
    for (int j = 0; j < 8; ++j) pk[j] = f2bf(acc[j]);
    *(ushort4*)(wA + ((size_t)(t * 16 + chunk) * 64 + lane) * 8) =
        make_ushort4(pk[0], pk[1], pk[2], pk[3]);
    *(ushort4*)(wA + ((size_t)(t * 16 + chunk) * 64 + lane) * 8 + 4) =
        make_ushort4(pk[4], pk[5], pk[6], pk[7]);
    if (chunk == 0 && lane < KK) {
      float tbv = 0.f;
      for (int k = 0; k < COMP; ++k)
        tbv += w2[(size_t)(lane * COMP + k) * 9 + t] * b1[k];
      ws[TB_OFF + lane * 9 + t] = tbv;
    }
  }
}

// ---------------------------------------------------------------------------
// Fused conv + softmax + gather: grid (HO, BN) = 256 blocks, 1024 thr = 16 wv.
// Conv: wave wv owns K-slice of 16 channels, both 32-px tiles (wt 0,1):
//   9 taps x (1 A-frag shared + 2 B-frags) = 18 MFMA/wave.
// LDS tree 16->8->4->2->1, wave 0 softmax -> sm in LDS (no global round-trip).
// Gather: wave wv owns 16 channels; x fp32 float2+shuffle, prefetched before
// the reduction barriers so the loads fly during tree+softmax.
// C/D layout: col(px)=lane&31, row(m)=(reg&3)+8*(reg>>2)+4*(lane>>5).
// ---------------------------------------------------------------------------
__global__ __launch_bounds__(1024, 4) void conv_softmax_gather(
    const float* __restrict__ ws, const float* __restrict__ b2,
    const float* __restrict__ x, float* __restrict__ out) {
  const int ho = blockIdx.x, b = blockIdx.y;
  const int tid = threadIdx.x;
  const int lane = tid & 63;
  const int wv = tid >> 6;                     // 0..15 = K-slice / ch-group
  const int n = lane & 31, half = lane >> 5;
  const ushort* xT = (const ushort*)(ws + XT_OFF);
  const ushort* wA = (const ushort*)ws;
  const int coff = wv * 16 + half * 8;
  const v8s zero8 = {};
  v16f acc[2] = {{}, {}};

  __shared__ float red[8 * KK * 64];           // 51200 B
  __shared__ float sml[KK * 64];               //  6400 B

  // ---------------- Phase 1: conv via MFMA ----------------
#pragma unroll
  for (int dr = 0; dr < 3; ++dr) {
    const int r = 2 * ho + dr - 1;
    if (r < 0) continue;                       // block-uniform (ho==0, dr==0)
#pragma unroll
    for (int dc = 0; dc < 3; ++dc) {
      const int t = dr * 3 + dc;
      const ushort* ap = wA + ((size_t)(t * 16 + wv) * 64 + lane) * 8;
      v8s af = *(const v8s*)ap;
      const size_t rowbase = (size_t)((b * HN + r) * WN);
#pragma unroll
      for (int wt = 0; wt < 2; ++wt) {
        const int wo = wt * 32 + n;
        const int q = 2 * wo + dc - 1;
        const bool bad = q < 0;                // only lane n==0, wt==0, dc==0
        const int qc = bad ? 0 : q;
        const ushort* bp = xT + (rowbase + qc) * CN + coff;
        v8s bf = *(const v8s*)bp;
        if (dc == 0 && bad) bf = zero8;
        acc[wt] = __builtin_amdgcn_mfma_f32_32x32x16_bf16(af, bf, acc[wt], 0, 0, 0);
      }
    }
  }

  // ---------------- prefetch gather x loads (fly during tree+softmax) ------
  const int wo = lane;
  const int c_base = __builtin_amdgcn_readfirstlane(wv * 16);
  const float* __restrict__ xb = x + (size_t)(b * CN) * (HN * WN);
  const int col = 2 * wo;
  float2 g[2][5];
  auto load_g = [&](int ci, float2* dst) {
    const float* xc = xb + (size_t)(c_base + ci) * (HN * WN);
#pragma unroll
    for (int i = 0; i < 5; ++i) {
      int r = 2 * ho - 2 + i;
      dst[i] = (r >= 0 && r < HN) ? *(const float2*)(xc + r * WN + col)
                                  : make_float2(0.f, 0.f);
    }
  };
  load_g(0, g[0]);
  load_g(1, g[1]);

  // ---------------- Reduction 16 -> 8 -> 4 -> 2, then softmax --------------
  if (wv >= 8) {
#pragma unroll
    for (int wt = 0; wt < 2; ++wt)
#pragma unroll
      for (int rg = 0; rg < 16; ++rg) {
        int m = (rg & 3) + 8 * (rg >> 2) + 4 * half;
        if (m < KK) red[((wv - 8) * KK + m) * 64 + wt * 32 + n] = acc[wt][rg];
      }
  }
  __syncthreads();
  if (wv < 8) {
#pragma unroll
    for (int wt = 0; wt < 2; ++wt)
#pragma unroll
      for (int rg = 0; rg < 16; ++rg) {
        int m = (rg & 3) + 8 * (rg >> 2) + 4 * half;
        if (m < KK) red[(wv * KK + m) * 64 + wt * 32 + n] += acc[wt][rg];
      }
  }
  __syncthreads();
  if (wv < 4) {
#pragma unroll
    for (int m = 0; m < KK; ++m)
      red[(wv * KK + m) * 64 + wo] += red[((wv + 4) * KK + m) * 64 + wo];
  }
  __syncthreads();
  if (wv < 2) {
#pragma unroll
    for (int m = 0; m < KK; ++m)
      red[(wv * KK + m) * 64 + wo] += red[((wv + 2) * KK + m) * 64 + wo];
  }
  __syncthreads();
  if (tid < 64) {
    const float* tb = ws + TB_OFF;
    const float vr0 = (ho > 0) ? 1.f : 0.f;
    const float vq0 = (wo > 0) ? 1.f : 0.f;
    float logit[KK];
    float mx = -1e30f;
#pragma unroll
    for (int m = 0; m < KK; ++m) {
      const float* t9 = tb + m * 9;
      float l = b2[m]
              + vr0 * (vq0 * t9[0] + t9[1] + t9[2])
              +       (vq0 * t9[3] + t9[4] + t9[5])
              +       (vq0 * t9[6] + t9[7] + t9[8]);
      l += red[(0 * KK + m) * 64 + wo] + red[(1 * KK + m) * 64 + wo];
      logit[m] = l;
      mx = fmaxf(mx, l);
    }
    float ssum = 0.f;
#pragma unroll
    for (int m = 0; m < KK; ++m) {
      float e = __expf(logit[m] - mx);
      logit[m] = e;
      ssum += e;
    }
    float inv = 1.f / ssum;
#pragma unroll
    for (int m = 0; m < KK; ++m) sml[m * 64 + wo] = logit[m] * inv;
  }
  __syncthreads();

  // ---------------- Phase 2: CARAFE gather ----------------
  float smr[KK];
#pragma unroll
  for (int m = 0; m < KK; ++m) smr[m] = sml[m * 64 + wo];

  const float wok = (wo > 0) ? 1.f : 0.f;
  const float w63 = (wo < 63) ? 1.f : 0.f;
  for (int ci = 0; ci < 16; ++ci) {
    float2 v[5];
#pragma unroll
    for (int i = 0; i < 5; ++i) v[i] = g[ci & 1][i];
    if (ci + 2 < 16) load_g(ci + 2, g[ci & 1]);

    float acc2 = 0.f;
#pragma unroll
    for (int i = 0; i < 5; ++i) {
      float lx = wok * __shfl_up(v[i].x, 1, 64);    // col 2wo-2
      float ly = wok * __shfl_up(v[i].y, 1, 64);    // col 2wo-1
      float rx = w63 * __shfl_down(v[i].x, 1, 64);  // col 2wo+2
      acc2 += lx * smr[i * 5 + 0] + ly * smr[i * 5 + 1]
            + v[i].x * smr[i * 5 + 2] + v[i].y * smr[i * 5 + 3]
            + rx * smr[i * 5 + 4];
    }
    out[(((size_t)(b * CN + c_base + ci)) * HO + ho) * WO + wo] = acc2;
  }
}

// ============================ FALLBACK PATH ================================
// Round-2 proven kernels (used only if ws_size < WS_NEED).
#define FB_WSTRIDE 240
#define FB_TB_OFF  (256 * FB_WSTRIDE)

__global__ __launch_bounds__(256) void compose_w_fb(
    const float* __restrict__ w1, const float* __restrict__ b1,
    const float* __restrict__ w2, float* __restrict__ ws) {
  int mt = blockIdx.x, c = threadIdx.x;
  float acc = 0.f;
#pragma unroll 8
  for (int k = 0; k < COMP; ++k)
    acc += w2[(size_t)(mt / 9 * COMP + k) * 9 + (mt % 9)] * w1[k * CN + c];
  ws[c * FB_WSTRIDE + mt] = acc;
  if (mt < FB_WSTRIDE - 225) ws[c * FB_WSTRIDE + 225 + mt] = 0.f;
  if (c == 0) {
    float tbv = 0.f;
    for (int k = 0; k < COMP; ++k)
      tbv += w2[(size_t)(mt / 9 * COMP + k) * 9 + (mt % 9)] * b1[k];
    ws[FB_TB_OFF + mt] = tbv;
  }
}

__global__ __launch_bounds__(1024, 4) void fused_fb(
    const float* __restrict__ x, const float* __restrict__ b2,
    const float* __restrict__ ws, float* __restrict__ out) {
  const int ho = blockIdx.x, b = blockIdx.y, tid = threadIdx.x;
  const int wo = tid & 63, wv = tid >> 6;
  const int c_base = __builtin_amdgcn_readfirstlane(wv * 16);
  const float* __restrict__ w2c = ws;
  const float* __restrict__ tb  = ws + FB_TB_OFF;
  __shared__ float red[8 * KK * 64];
  __shared__ float sm[KK * 64];
  const float* __restrict__ xb = x + (size_t)(b * CN) * (HN * WN);
  const int col = 2 * wo;
  float acc[KK];
#pragma unroll
  for (int m = 0; m < KK; ++m) acc[m] = 0.f;
  float2 xbuf[2][3];
  auto load_ch = [&](int ci, float2* dst) {
    const float* xc = xb + (size_t)(c_base + ci) * (HN * WN);
    dst[0] = (ho > 0) ? *(const float2*)(xc + (2 * ho - 1) * WN + col)
                      : make_float2(0.f, 0.f);
    dst[1] = *(const float2*)(xc + (2 * ho) * WN + col);
    dst[2] = *(const float2*)(xc + (2 * ho + 1) * WN + col);
  };
  load_ch(0, xbuf[0]);
  load_ch(1, xbuf[1]);
  const float wok = (wo > 0) ? 1.f : 0.f;
  for (int ci = 0; ci < 16; ++ci) {
    float2 r0 = xbuf[ci & 1][0], r1 = xbuf[ci & 1][1], r2 = xbuf[ci & 1][2];
    if (ci + 2 < 16) load_ch(ci + 2, xbuf[ci & 1]);
    float xv[9];
    xv[0] = wok * __shfl_up(r0.y, 1, 64); xv[1] = r0.x; xv[2] = r0.y;
    xv[3] = wok * __shfl_up(r1.y, 1, 64); xv[4] = r1.x; xv[5] = r1.y;
    xv[6] = wok * __shfl_up(r2.y, 1, 64); xv[7] = r2.x; xv[8] = r2.y;
    const float* __restrict__ wrow = w2c + (size_t)(c_base + ci) * FB_WSTRIDE;
#pragma unroll
    for (int m = 0; m < KK; ++m) {
      float a = acc[m];
#pragma unroll
      for (int t = 0; t < 9; ++t) a += wrow[m * 9 + t] * xv[t];
      acc[m] = a;
    }
  }
  float2 g[2][5];
  auto load_g = [&](int ci, float2* dst) {
    const float* xc = xb + (size_t)(c_base + ci) * (HN * WN);
#pragma unroll
    for (int i = 0; i < 5; ++i) {
      int r = 2 * ho - 2 + i;
      dst[i] = (r >= 0 && r < HN) ? *(const float2*)(xc + r * WN + col)
                                  : make_float2(0.f, 0.f);
    }
  };
  load_g(0, g[0]);
  load_g(1, g[1]);
  if (wv >= 8) {
#pragma unroll
    for (int m = 0; m < KK; ++m) red[((wv - 8) * KK + m) * 64 + wo] = acc[m];
  }
  __syncthreads();
  if (wv < 8) {
#pragma unroll
    for (int m = 0; m < KK; ++m) red[(wv * KK + m) * 64 + wo] += acc[m];
  }
  __syncthreads();
  if (wv < 4) {
#pragma unroll
    for (int m = 0; m < KK; ++m)
      red[(wv * KK + m) * 64 + wo] += red[((wv + 4) * KK + m) * 64 + wo];
  }
  __syncthreads();
  if (wv < 2) {
#pragma unroll
    for (int m = 0; m < KK; ++m)
      red[(wv * KK + m) * 64 + wo] += red[((wv + 2) * KK + m) * 64 + wo];
  }
  __syncthreads();
  if (tid < 64) {
    const float vr0 = (ho > 0) ? 1.f : 0.f;
    const float vq0 = (wo > 0) ? 1.f : 0.f;
    float logit[KK];
    float mx = -1e30f;
#pragma unroll
    for (int m = 0; m < KK; ++m) {
      const float* t9 = tb + m * 9;
      float l = b2[m]
              + vr0 * (vq0 * t9[0] + t9[1] + t9[2])
              +       (vq0 * t9[3] + t9[4] + t9[5])
              +       (vq0 * t9[6] + t9[7] + t9[8]);
      l += red[(0 * KK + m) * 64 + wo] + red[(1 * KK + m) * 64 + wo];
      logit[m] = l;
      mx = fmaxf(mx, l);
    }
    float s = 0.f;
#pragma unroll
    for (int m = 0; m < KK; ++m) {
      float e = __expf(logit[m] - mx);
      logit[m] = e;
      s += e;
    }
    float inv = 1.f / s;
#pragma unroll
    for (int m = 0; m < KK; ++m) sm[m * 64 + wo] = logit[m] * inv;
  }
  __syncthreads();
  float smr[KK];
#pragma unroll
  for (int m = 0; m < KK; ++m) smr[m] = sm[m * 64 + wo];
  const float w63 = (wo < 63) ? 1.f : 0.f;
  for (int ci = 0; ci < 16; ++ci) {
    float2 v[5];
#pragma unroll
    for (int i = 0; i < 5; ++i) v[i] = g[ci & 1][i];
    if (ci + 2 < 16) load_g(ci + 2, g[ci & 1]);
    float acc2 = 0.f;
#pragma unroll
    for (int i = 0; i < 5; ++i) {
      float lx = wok * __shfl_up(v[i].x, 1, 64);
      float ly = wok * __shfl_up(v[i].y, 1, 64);
      float rx = w63 * __shfl_down(v[i].x, 1, 64);
      acc2 += lx * smr[i * 5 + 0] + ly * smr[i * 5 + 1]
            + v[i].x * smr[i * 5 + 2] + v[i].y * smr[i * 5 + 3]
            + rx * smr[i * 5 + 4];
    }
    out[(((size_t)(b * CN + c_base + ci)) * HO + ho) * WO + wo] = acc2;
  }
}

// ---------------------------------------------------------------------------
extern "C" void kernel_launch(void* const* d_in, const int* in_sizes, int n_in,
                              void* d_out, int out_size, void* d_ws, size_t ws_size,
                              hipStream_t stream) {
  const float* x  = (const float*)d_in[0];
  const float* w1 = (const float*)d_in[1];
  const float* b1 = (const float*)d_in[2];
  const float* w2 = (const float*)d_in[3];
  const float* b2 = (const float*)d_in[4];
  float* out = (float*)d_out;
  float* ws  = (float*)d_ws;

  if (ws_size >= WS_NEED) {
    hipLaunchKernelGGL(prep_kernel, dim3(4096 + 36), dim3(256), 0, stream,
                       x, w1, b1, w2, ws);
    hipLaunchKernelGGL(conv_softmax_gather, dim3(HO, BN), dim3(1024), 0, stream,
                       ws, b2, x, out);
  } else {
    hipLaunchKernelGGL(compose_w_fb, dim3(225), dim3(256), 0, stream,
                       w1, b1, w2, ws);
    hipLaunchKernelGGL(fused_fb, dim3(HO, BN), dim3(1024), 0, stream,
                       x, b2, ws, out);
  }
}